// Round 3
// baseline (5386.666 us; speedup 1.0000x reference)
//
#include <hip/hip_runtime.h>
#include <math.h>

// MFFNet forward on MI355X. Inputs/outputs fp32; GEMMs run bf16 MFMA with
// fp32 accumulation. Intermediates consumed only by GEMMs are stored bf16
// (identical rounding to staging); residual/LN paths stay fp32.
// Workspace ~158 MB with lifetime-based aliasing (see kernel_launch).

typedef unsigned short u16;                                 // raw bf16 storage
typedef __attribute__((ext_vector_type(8))) short short8;   // 8 bf16 = 4 VGPRs
typedef __attribute__((ext_vector_type(4))) float floatx4;

#define DD 768
#define TT 512
#define BB 8
#define MM 4096      // B*T rows
#define FFN 3072

__device__ __forceinline__ float b2f(u16 u) {
  union { unsigned u32; float f; } x; x.u32 = ((unsigned)u) << 16; return x.f;
}
__device__ __forceinline__ u16 f2b(float f) {   // round-to-nearest-even
  union { float f; unsigned u; } x; x.f = f;
  unsigned r = x.u + 0x7FFFu + ((x.u >> 16) & 1u);
  return (u16)(r >> 16);
}

// ---------------------------------------------------------------------------
// Universal GEMM: C[M,N] = act(A[M,K] @ W[N,K]^T + bias + resid) [*rowScale]
// A/W globals either fp32 (converted to bf16 at staging) or bf16 (raw).
// ntaps/pad: conv-over-T mode (tap reads A row r+tap-pad within its T-batch).
// rowScale: per-row scale indexed [ (row>>9) * rsStride ] (align fusion).
// accum: C += v (fp32 out only). OP: 0=none 1=relu 2=gelu 3=sigmoid.
// ---------------------------------------------------------------------------
template<int OP>
__global__ __launch_bounds__(256)
void gemm_bt(const void* __restrict__ Av, const void* __restrict__ Wv,
             const float* __restrict__ bias, const float* __restrict__ resid,
             void* __restrict__ Cv,
             int M, int N, int K,
             int aBf16, int wBf16, int outBf16,
             int ntaps, int pad, long wtapStride,
             const float* __restrict__ rowScale, int rsStride, int accum,
             long aBatch, long wBatch, long cBatch)
{
  __shared__ __align__(16) u16 sA[128 * 64];
  __shared__ __align__(16) u16 sB[128 * 64];
  const int tid  = threadIdx.x;
  const int lane = tid & 63;
  const int wv   = tid >> 6;
  const int m0 = blockIdx.y * 128;
  const int n0 = blockIdx.x * 128;

  floatx4 acc[4][4];
#pragma unroll
  for (int i = 0; i < 4; ++i)
#pragma unroll
    for (int j = 0; j < 4; ++j) acc[i][j] = (floatx4){0.f, 0.f, 0.f, 0.f};

  const int wr = (wv >> 1) * 64;        // wave's 64x64 quadrant
  const int wc = (wv & 1) * 64;
  const int mrow = lane & 15;
  const int ksub = (lane >> 4) * 8;

  for (int tap = 0; tap < ntaps; ++tap) {
    const int dt = tap - pad;
    for (int k0 = 0; k0 < K; k0 += 64) {
      // ---- stage A tile 128x64 ----
      if (aBf16) {
        const u16* Ab = (const u16*)Av + (long)blockIdx.z * aBatch;
#pragma unroll
        for (int it = 0; it < 4; ++it) {
          int slot = it * 256 + tid;
          int row = slot >> 3;          // 0..127
          int col = (slot & 7) * 8;
          int gr = m0 + row;
          int t  = gr & (TT - 1);
          uint4 v = make_uint4(0u, 0u, 0u, 0u);
          if ((unsigned)(t + dt) < (unsigned)TT)
            v = *(const uint4*)(Ab + (long)(gr + dt) * K + k0 + col);
          *(uint4*)(sA + row * 64 + col) = v;
        }
      } else {
        const float* Af = (const float*)Av + (long)blockIdx.z * aBatch;
#pragma unroll
        for (int it = 0; it < 8; ++it) {
          int slot = it * 256 + tid;
          int row = slot >> 4;          // 0..127
          int col = (slot & 15) * 4;
          int gr = m0 + row;
          int t  = gr & (TT - 1);
          float4 v = make_float4(0.f, 0.f, 0.f, 0.f);
          if ((unsigned)(t + dt) < (unsigned)TT)
            v = *(const float4*)(Af + (long)(gr + dt) * K + k0 + col);
          ushort4 h; h.x = f2b(v.x); h.y = f2b(v.y); h.z = f2b(v.z); h.w = f2b(v.w);
          *(ushort4*)(sA + row * 64 + col) = h;
        }
      }
      // ---- stage W tile 128x64 ----
      if (wBf16) {
        const u16* Wb = (const u16*)Wv + (long)blockIdx.z * wBatch + (long)tap * wtapStride;
#pragma unroll
        for (int it = 0; it < 4; ++it) {
          int slot = it * 256 + tid;
          int row = slot >> 3;
          int col = (slot & 7) * 8;
          int gn = n0 + row;
          uint4 v = make_uint4(0u, 0u, 0u, 0u);
          if (gn < N) v = *(const uint4*)(Wb + (long)gn * K + k0 + col);
          *(uint4*)(sB + row * 64 + col) = v;
        }
      } else {
        const float* Wb = (const float*)Wv + (long)blockIdx.z * wBatch + (long)tap * wtapStride;
#pragma unroll
        for (int it = 0; it < 8; ++it) {
          int slot = it * 256 + tid;
          int row = slot >> 4;
          int col = (slot & 15) * 4;
          int gn = n0 + row;
          float4 v = make_float4(0.f, 0.f, 0.f, 0.f);
          if (gn < N) v = *(const float4*)(Wb + (long)gn * K + k0 + col);
          ushort4 h; h.x = f2b(v.x); h.y = f2b(v.y); h.z = f2b(v.z); h.w = f2b(v.w);
          *(ushort4*)(sB + row * 64 + col) = h;
        }
      }
      __syncthreads();
#pragma unroll
      for (int kb = 0; kb < 64; kb += 32) {
        short8 af[4], bfr[4];
#pragma unroll
        for (int i = 0; i < 4; ++i)
          af[i] = *(const short8*)(sA + (wr + i * 16 + mrow) * 64 + kb + ksub);
#pragma unroll
        for (int j = 0; j < 4; ++j)
          bfr[j] = *(const short8*)(sB + (wc + j * 16 + mrow) * 64 + kb + ksub);
#pragma unroll
        for (int i = 0; i < 4; ++i)
#pragma unroll
          for (int j = 0; j < 4; ++j)
            acc[i][j] = __builtin_amdgcn_mfma_f32_16x16x32_bf16(af[i], bfr[j], acc[i][j], 0, 0, 0);
      }
      __syncthreads();
    }
  }

  // epilogue: C/D layout col=lane&15, row=(lane>>4)*4+reg (m89-verified)
  const int cn = lane & 15;
  const int rq = (lane >> 4) * 4;
  u16*   Ch = (u16*)Cv   + (long)blockIdx.z * cBatch;
  float* Cf = (float*)Cv + (long)blockIdx.z * cBatch;
#pragma unroll
  for (int j = 0; j < 4; ++j) {
    int gn = n0 + wc + j * 16 + cn;
    if (gn >= N) continue;
    float bv = bias ? bias[gn] : 0.f;
#pragma unroll
    for (int i = 0; i < 4; ++i) {
#pragma unroll
      for (int r = 0; r < 4; ++r) {
        int gm = m0 + wr + i * 16 + rq + r;
        float v = acc[i][j][r] + bv;
        if (resid) v += resid[(long)gm * N + gn];
        if (OP == 1) v = fmaxf(v, 0.f);
        if (OP == 2) v = 0.5f * v * (1.f + erff(v * 0.70710678118654752440f));
        if (OP == 3) v = 1.f / (1.f + expf(-v));
        if (rowScale) v *= rowScale[(gm >> 9) * rsStride];
        long idx = (long)gm * N + gn;
        if (outBf16) Ch[idx] = f2b(v);
        else if (accum) Cf[idx] += v;
        else Cf[idx] = v;
      }
    }
  }
  (void)M;
}

// ---------------------------------------------------------------------------
// LayerNorm over D=768, fp32 in; out fp32 (optionally accumulated) or bf16.
// ---------------------------------------------------------------------------
__global__ void ln_kernel(const float* __restrict__ x,
                          const float* __restrict__ w, const float* __restrict__ b,
                          void* __restrict__ y, int outBf16, int accum)
{
  const int row = blockIdx.x;
  const int tid = threadIdx.x;
  __shared__ float rs[256], rq[256];
  float v[3];
  long base = (long)row * DD;
  float s = 0.f, q = 0.f;
#pragma unroll
  for (int i = 0; i < 3; ++i) {
    int c = tid + i * 256;
    float t = x[base + c];
    v[i] = t; s += t; q += t * t;
  }
  rs[tid] = s; rq[tid] = q; __syncthreads();
  for (int st = 128; st > 0; st >>= 1) {
    if (tid < st) { rs[tid] += rs[tid + st]; rq[tid] += rq[tid + st]; }
    __syncthreads();
  }
  float mean = rs[0] * (1.f / DD);
  float var  = fmaxf(rq[0] * (1.f / DD) - mean * mean, 0.f);
  float rstd = rsqrtf(var + 1e-12f);
#pragma unroll
  for (int i = 0; i < 3; ++i) {
    int c = tid + i * 256;
    float o = ((v[i] - mean) * rstd) * w[c] + b[c];
    if (outBf16) ((u16*)y)[base + c] = f2b(o);
    else if (accum) ((float*)y)[base + c] += o;
    else ((float*)y)[base + c] = o;
  }
}

// rm[b][d] = mean over T of f[b,t,d]; launched per stream
__global__ void rowmean_kernel(const float* __restrict__ f, float* __restrict__ rm)
{
  int b = blockIdx.x / 3, chunk = blockIdx.x % 3;
  int d = chunk * 256 + threadIdx.x;
  const float* base = f + (long)b * TT * DD + d;
  float s = 0.f;
  for (int t = 0; t < TT; ++t) s += base[(long)t * DD];
  rm[b * DD + d] = s * (1.f / TT);
}

// cs[n][e] = sum over d of align_w[n][d][e]
__global__ void colsum_kernel(const float* __restrict__ w, float* __restrict__ cs)
{
  int n = blockIdx.x / 3, chunk = blockIdx.x % 3;
  int e = chunk * 256 + threadIdx.x;
  const float* base = w + (long)n * DD * DD + e;
  float s = 0.f;
  for (int d = 0; d < DD; ++d) s += base[(long)d * DD];
  cs[n * DD + e] = s;
}

// m[b,n] = mean(A_n[b]) analytically; wplus = softmax(relu(...)) + 1/6
__global__ void fusion_weights(const float* __restrict__ rm, const float* __restrict__ cs,
                               const float* __restrict__ align_b,
                               const float* __restrict__ aw, const float* __restrict__ ab,
                               float* __restrict__ wplus)
{
  __shared__ float msh[48];
  int tid = threadIdx.x;
  if (tid < 48) {
    int b = tid / 6, n = tid % 6;
    const float* r = rm + ((long)n * BB + b) * DD;
    const float* c = cs + n * DD;
    float dot = 0.f, bs = 0.f;
    for (int e = 0; e < DD; ++e) dot += r[e] * c[e];
    for (int d = 0; d < DD; ++d) bs += align_b[n * DD + d];
    msh[b * 6 + n] = (dot + bs) * (1.f / DD);
  }
  __syncthreads();
  if (tid < BB) {
    int b = tid;
    float z[6];
#pragma unroll
    for (int n = 0; n < 6; ++n) {
      float s = ab[n];
#pragma unroll
      for (int j = 0; j < 6; ++j)
        s += (aw[n * 12 + j] + aw[n * 12 + 6 + j]) * msh[b * 6 + j];
      z[n] = fmaxf(s, 0.f);
    }
    float mx = z[0];
#pragma unroll
    for (int n = 1; n < 6; ++n) mx = fmaxf(mx, z[n]);
    float se = 0.f, e[6];
#pragma unroll
    for (int n = 0; n < 6; ++n) { e[n] = expf(z[n] - mx); se += e[n]; }
#pragma unroll
    for (int n = 0; n < 6; ++n) wplus[b * 6 + n] = e[n] / se + (1.f / 6.f);
  }
}

// cc = [Et | Ea] row-wise, fp32 -> bf16
__global__ void concat_kernel(const float* __restrict__ Et, const float* __restrict__ Ea,
                              u16* __restrict__ cc)
{
  long e = (long)blockIdx.x * 256 + threadIdx.x;
  if (e >= (long)MM * 1536) return;
  int c = (int)(e % 1536);
  long r = e / 1536;
  float v = (c < 768) ? Et[r * 768 + c] : Ea[r * 768 + c - 768];
  cc[e] = f2b(v);
}

// Ef = g*Ea + (1-g)*Et, in place over Et (all fp32)
__global__ void ef_kernel(const float* __restrict__ g, const float* __restrict__ Ea,
                          float* __restrict__ EtEf)
{
  long e = (long)blockIdx.x * 256 + threadIdx.x;
  if (e >= (long)MM * DD) return;
  float gv = g[e];
  EtEf[e] = gv * Ea[e] + (1.f - gv) * EtEf[e];
}

// conv weight [O,I,KT] fp32 -> [KT][O][I] bf16
__global__ void repack_conv(const float* __restrict__ src, u16* __restrict__ dst, int KT)
{
  long e = (long)blockIdx.x * 256 + threadIdx.x;
  if (e >= (long)KT * DD * DD) return;
  int k = (int)(e / (DD * DD));
  int rem = (int)(e - (long)k * DD * DD);
  int o = rem / DD, i = rem % DD;
  dst[e] = f2b(src[((long)o * DD + i) * KT + k]);
}

// out[row,h] = (X[row,:] . Wt[h,:] + bias[h]) * scale ; H=12, one wave per row
__global__ void lin_small(const float* __restrict__ X, const float* __restrict__ Wt,
                          const float* __restrict__ bias, float scale,
                          float* __restrict__ out)
{
  int row = blockIdx.x * 4 + (threadIdx.x >> 6);
  int lane = threadIdx.x & 63;
  float acc[12];
#pragma unroll
  for (int h = 0; h < 12; ++h) acc[h] = 0.f;
  for (int k = lane; k < DD; k += 64) {
    float xv = X[(long)row * DD + k];
#pragma unroll
    for (int h = 0; h < 12; ++h) acc[h] += xv * Wt[h * DD + k];
  }
#pragma unroll
  for (int h = 0; h < 12; ++h)
    for (int off = 32; off > 0; off >>= 1) acc[h] += __shfl_down(acc[h], off);
  if (lane == 0) {
#pragma unroll
    for (int h = 0; h < 12; ++h)
      out[(long)row * 12 + h] = (acc[h] + bias[h]) * scale;
  }
}

// scores over h=12 then softmax over c=512 -> aw (bf16)
__global__ void scores_softmax(const float* __restrict__ qs, const float* __restrict__ ks,
                               u16* __restrict__ aw)
{
  int bs = blockIdx.x;            // b*512+s
  int b = bs >> 9;
  int tid = threadIdx.x;
  __shared__ float qsh[12];
  __shared__ float red[256];
  if (tid < 12) qsh[tid] = qs[(long)bs * 12 + tid];
  __syncthreads();
  float sc[2];
#pragma unroll
  for (int p = 0; p < 2; ++p) {
    int c = tid + p * 256;
    const float* kr = ks + (long)(b * 512 + c) * 12;
    float v = 0.f;
#pragma unroll
    for (int h = 0; h < 12; ++h) v += qsh[h] * kr[h];
    sc[p] = v;
  }
  red[tid] = fmaxf(sc[0], sc[1]); __syncthreads();
  for (int st = 128; st > 0; st >>= 1) {
    if (tid < st) red[tid] = fmaxf(red[tid], red[tid + st]);
    __syncthreads();
  }
  float mx = red[0]; __syncthreads();
  float e0 = expf(sc[0] - mx), e1 = expf(sc[1] - mx);
  red[tid] = e0 + e1; __syncthreads();
  for (int st = 128; st > 0; st >>= 1) {
    if (tid < st) red[tid] += red[tid + st];
    __syncthreads();
  }
  float inv = 1.f / red[0];
  aw[(long)bs * 512 + tid]       = f2b(e0 * inv);
  aw[(long)bs * 512 + tid + 256] = f2b(e1 * inv);
}

// per-b transpose kk[b] [512,768] fp32 -> kkT[b] [768,512] bf16
__global__ void transpose_kernel(const float* __restrict__ in, u16* __restrict__ out)
{
  int b = blockIdx.z;
  const float* ib = in + (long)b * TT * DD;
  u16* ob = out + (long)b * TT * DD;
  __shared__ float tile[32][33];
  int c0 = blockIdx.x * 32;   // d
  int r0 = blockIdx.y * 32;   // t
  int tx = threadIdx.x, ty = threadIdx.y;
#pragma unroll
  for (int i = 0; i < 4; ++i)
    tile[ty + 8 * i][tx] = ib[(long)(r0 + ty + 8 * i) * DD + c0 + tx];
  __syncthreads();
#pragma unroll
  for (int i = 0; i < 4; ++i)
    ob[(long)(c0 + ty + 8 * i) * TT + r0 + tx] = f2b(tile[tx][ty + 8 * i]);
}

// ---------------------------------------------------------------------------
extern "C" void kernel_launch(void* const* d_in, const int* in_sizes, int n_in,
                              void* d_out, int out_size, void* d_ws, size_t ws_size,
                              hipStream_t stream)
{
  (void)in_sizes; (void)n_in; (void)out_size; (void)ws_size;
  const float* f[6];
  for (int i = 0; i < 6; ++i) f[i] = (const float*)d_in[i];
  const float* Ea      = (const float*)d_in[6];
  const float* align_w = (const float*)d_in[7];
  const float* align_b = (const float*)d_in[8];
  const float* att_w   = (const float*)d_in[9];
  const float* att_b   = (const float*)d_in[10];
  const float* g1_w = (const float*)d_in[11]; const float* g1_b = (const float*)d_in[12];
  const float* g2_w = (const float*)d_in[13]; const float* g2_b = (const float*)d_in[14];
  const float* g3_w = (const float*)d_in[15]; const float* g3_b = (const float*)d_in[16];
  const float* g4_w = (const float*)d_in[17]; const float* g4_b = (const float*)d_in[18];
  const float* ln_w = (const float*)d_in[19]; const float* ln_b = (const float*)d_in[20];
  const float* c1_w = (const float*)d_in[21]; const float* c1_b = (const float*)d_in[22];
  const float* c3_w = (const float*)d_in[23]; const float* c3_b = (const float*)d_in[24];
  const float* c5_w = (const float*)d_in[25]; const float* c5_b = (const float*)d_in[26];
  const float* q_w  = (const float*)d_in[27]; const float* q_b  = (const float*)d_in[28];
  const float* qa_w = (const float*)d_in[29]; const float* qa_b = (const float*)d_in[30];
  const float* k_w  = (const float*)d_in[31]; const float* k_b  = (const float*)d_in[32];
  const float* ka_w = (const float*)d_in[33]; const float* ka_b = (const float*)d_in[34];
  const float* tr_w = (const float*)d_in[35]; const float* tr_b = (const float*)d_in[36];
  const float* ao_w = (const float*)d_in[37]; const float* ao_b = (const float*)d_in[38];
  const float* fln_w = (const float*)d_in[39]; const float* fln_b = (const float*)d_in[40];
  const float* fi_w = (const float*)d_in[41]; const float* fi_b = (const float*)d_in[42];
  const float* fo_w = (const float*)d_in[43]; const float* fo_b = (const float*)d_in[44];
  const float* m1_w = (const float*)d_in[45]; const float* m1_b = (const float*)d_in[46];
  const float* m2_w = (const float*)d_in[47]; const float* m2_b = (const float*)d_in[48];
  const float* out_w = (const float*)d_in[49]; const float* out_b = (const float*)d_in[50];

  char* ws = (char*)d_ws;
  size_t off = 0;
  auto alloc = [&](size_t bytes) -> char* {
    char* p = ws + off;
    off += bytes;
    off = (off + 255) & ~(size_t)255;
    return p;
  };
  const long MD = (long)MM * DD;        // 3,145,728 elements

  // small fp32 scratch
  float* rmb   = (float*)alloc(6L * BB * DD * 4);   // row-means per stream
  float* csb   = (float*)alloc(6L * DD * 4);        // weight col-sums
  float* wplus = (float*)alloc(48 * 4);
  float* qsf   = (float*)alloc((long)MM * 12 * 4);
  float* ksf   = (float*)alloc((long)MM * 12 * 4);
  // big regions (sizes in bytes; aliased by phase, lifetimes hand-checked)
  char* R_cc = alloc(MD * 4);           // cc(b16 M*1536) -> qbuf(f32) -> outp(f32)
  char* R_o1 = alloc(MD * 4);           // o1(b16 M*1536) -> kkbuf(f32) -> attb(f32)
  char* R_o2 = alloc(MD * 4);           // o2(b16 M*1536) -> selfb(b16)
  char* R_o3 = alloc(MD * 2);           // o3(b16) -> ctxl(b16) -> Pn(b16)
  char* R_gb = alloc(MD * 4);           // g(f32) -> attp(f32) -> J(f32)
  char* R_Et = alloc(MD * 4);           // Et/Ef(f32) -> w3r+w5r(b16) -> kkT+awb(b16) -> Jn(b16)
  char* R_xb = alloc(MD * 4);           // x (f32, live to end)
  char* R_U  = alloc(3 * MD * 4);       // U1,U3,U5 (f32)
  char* R_P  = alloc(MD * 4);           // accumulated P (f32)
  char* R_in = alloc((long)MM * FFN * 2); // interb (b16)
  // total ~158 MB

  u16*   cc    = (u16*)R_cc;
  u16*   o1    = (u16*)R_o1;
  u16*   o2    = (u16*)R_o2;
  u16*   o3    = (u16*)R_o3;
  float* gb    = (float*)R_gb;
  float* Et    = (float*)R_Et;
  float* xb    = (float*)R_xb;
  float* U1    = (float*)R_U;
  float* U3    = (float*)(R_U + MD * 4);
  float* U5    = (float*)(R_U + 2 * MD * 4);
  float* Pacc  = (float*)R_P;
  u16*   interb = (u16*)R_in;
  u16*   w3r   = (u16*)R_Et;                         // 3*D*D b16 = 3.5 MB
  u16*   w5r   = (u16*)(R_Et + 3L * 589824 * 2);     // 5*D*D b16 = 5.9 MB
  float* qbuf  = (float*)R_cc;
  float* kkbuf = (float*)R_o1;
  u16*   kkT   = (u16*)R_Et;                         // 8*768*512 b16 = 6.3 MB
  u16*   awb   = (u16*)(R_Et + (long)BB * DD * TT * 2); // 8*512*512 b16 = 4.2 MB
  u16*   ctxl  = (u16*)R_o3;
  u16*   selfb = (u16*)R_o2;
  float* attp  = (float*)R_gb;
  float* attb  = (float*)R_o1;
  float* outp  = (float*)R_cc;
  u16*   Pn    = (u16*)R_o3;
  float* Jb    = (float*)R_gb;
  u16*   Jn    = (u16*)R_Et;

  auto gemm = [&](int op, const void* A, const void* W, const float* bias,
                  const float* resid, void* Cc, int Mi, int Ni, int Ki,
                  int aB, int wB, int oB,
                  int ntaps, int pad, long wtap,
                  const float* rsc, int rss, int acc,
                  int batch, long ab, long wb, long cb) {
    dim3 g((Ni + 127) / 128, (Mi + 127) / 128, batch);
    if (op == 0)      gemm_bt<0><<<g, 256, 0, stream>>>(A, W, bias, resid, Cc, Mi, Ni, Ki, aB, wB, oB, ntaps, pad, wtap, rsc, rss, acc, ab, wb, cb);
    else if (op == 1) gemm_bt<1><<<g, 256, 0, stream>>>(A, W, bias, resid, Cc, Mi, Ni, Ki, aB, wB, oB, ntaps, pad, wtap, rsc, rss, acc, ab, wb, cb);
    else if (op == 2) gemm_bt<2><<<g, 256, 0, stream>>>(A, W, bias, resid, Cc, Mi, Ni, Ki, aB, wB, oB, ntaps, pad, wtap, rsc, rss, acc, ab, wb, cb);
    else              gemm_bt<3><<<g, 256, 0, stream>>>(A, W, bias, resid, Cc, Mi, Ni, Ki, aB, wB, oB, ntaps, pad, wtap, rsc, rss, acc, ab, wb, cb);
  };
  const int EW  = (int)((MD + 255) / 256);
  const int EW2 = (int)((MD * 2 + 255) / 256);

  // --- fusion weights (analytic means, before the big GEMMs) ---
  for (int n = 0; n < 6; ++n)
    rowmean_kernel<<<24, 256, 0, stream>>>(f[n], rmb + (long)n * BB * DD);
  colsum_kernel<<<18, 256, 0, stream>>>(align_w, csb);
  fusion_weights<<<1, 64, 0, stream>>>(rmb, csb, align_b, att_w, att_b, wplus);

  // --- FeatureAlignment accumulated directly into Et with row scales ---
  for (int n = 0; n < 6; ++n)
    gemm(0, f[n], align_w + (long)n * DD * DD, align_b + n * DD, nullptr, Et,
         MM, DD, DD, 0, 0, 0, 1, 0, 0, wplus + n, 6, (n > 0) ? 1 : 0, 1, 0, 0, 0);

  // --- GatedFusion ---
  concat_kernel<<<EW2, 256, 0, stream>>>(Et, Ea, cc);
  gemm(1, cc, g1_w, g1_b, nullptr, o1, MM, 1536, 1536, 1, 0, 1, 1, 0, 0, nullptr, 0, 0, 1, 0, 0, 0);
  gemm(1, o1, g2_w, g2_b, nullptr, o2, MM, 1536, 1536, 1, 0, 1, 1, 0, 0, nullptr, 0, 0, 1, 0, 0, 0);
  gemm(1, o2, g3_w, g3_b, nullptr, o3, MM, DD, 1536, 1, 0, 1, 1, 0, 0, nullptr, 0, 0, 1, 0, 0, 0);
  gemm(3, o3, g4_w, g4_b, nullptr, gb, MM, DD, DD, 1, 0, 0, 1, 0, 0, nullptr, 0, 0, 1, 0, 0, 0);
  ef_kernel<<<EW, 256, 0, stream>>>(gb, Ea, Et);          // Ef in place

  // --- MSFastformer front ---
  ln_kernel<<<MM, 256, 0, stream>>>(Et, ln_w, ln_b, xb, 0, 0);   // x
  repack_conv<<<(3 * 589824 + 255) / 256, 256, 0, stream>>>(c3_w, w3r, 3);
  repack_conv<<<(5 * 589824 + 255) / 256, 256, 0, stream>>>(c5_w, w5r, 5);
  gemm(0, xb, c1_w, c1_b, nullptr, U1, MM, DD, DD, 0, 0, 0, 1, 0, 0, nullptr, 0, 0, 1, 0, 0, 0);
  gemm(0, xb, w3r, c3_b, nullptr, U3, MM, DD, DD, 0, 1, 0, 3, 1, 589824, nullptr, 0, 0, 1, 0, 0, 0);
  gemm(0, xb, w5r, c5_b, nullptr, U5, MM, DD, DD, 0, 1, 0, 5, 2, 589824, nullptr, 0, 0, 1, 0, 0, 0);

  // --- fastformer layers (shared weights); P accumulated across layers ---
  auto fastformer = [&](const float* hid, const float* ctx, int layer) {
    gemm(0, hid, q_w, q_b, nullptr, qbuf, MM, DD, DD, 0, 0, 0, 1, 0, 0, nullptr, 0, 0, 1, 0, 0, 0);
    gemm(0, ctx, k_w, k_b, nullptr, kkbuf, MM, DD, DD, 0, 0, 0, 1, 0, 0, nullptr, 0, 0, 1, 0, 0, 0);
    lin_small<<<MM / 4, 256, 0, stream>>>(qbuf, qa_w, qa_b, 0.125f, qsf);
    lin_small<<<MM / 4, 256, 0, stream>>>(kkbuf, ka_w, ka_b, 0.125f, ksf);
    scores_softmax<<<MM, 256, 0, stream>>>(qsf, ksf, awb);
    transpose_kernel<<<dim3(24, 16, 8), dim3(32, 8), 0, stream>>>(kkbuf, kkT);
    gemm(0, awb, kkT, nullptr, nullptr, ctxl, TT, DD, TT, 1, 1, 1, 1, 0, 0, nullptr, 0, 0,
         BB, (long)TT * TT, (long)DD * TT, (long)TT * DD);
    gemm(0, ctxl, tr_w, tr_b, qbuf, selfb, MM, DD, DD, 1, 0, 1, 1, 0, 0, nullptr, 0, 0, 1, 0, 0, 0);
    gemm(0, selfb, ao_w, ao_b, hid, attp, MM, DD, DD, 1, 0, 0, 1, 0, 0, nullptr, 0, 0, 1, 0, 0, 0);
    ln_kernel<<<MM, 256, 0, stream>>>(attp, fln_w, fln_b, attb, 0, 0);
    gemm(2, attb, fi_w, fi_b, nullptr, interb, MM, FFN, DD, 0, 0, 1, 1, 0, 0, nullptr, 0, 0, 1, 0, 0, 0);
    gemm(0, interb, fo_w, fo_b, attb, outp, MM, DD, FFN, 1, 0, 0, 1, 0, 0, nullptr, 0, 0, 1, 0, 0, 0);
    ln_kernel<<<MM, 256, 0, stream>>>(outp, fln_w, fln_b, Pacc, 0, (layer > 0) ? 1 : 0);
  };
  fastformer(U5, U3, 0);
  fastformer(U3, U1, 1);
  fastformer(U1, U5, 2);

  // --- tail ---
  ln_kernel<<<MM, 256, 0, stream>>>(Pacc, ln_w, ln_b, Pn, 1, 0);
  gemm(2, Pn, m1_w, m1_b, nullptr, interb, MM, FFN, DD, 1, 0, 1, 1, 0, 0, nullptr, 0, 0, 1, 0, 0, 0);
  gemm(0, interb, m2_w, m2_b, xb, Jb, MM, DD, FFN, 1, 0, 0, 1, 0, 0, nullptr, 0, 0, 1, 0, 0, 0);
  ln_kernel<<<MM, 256, 0, stream>>>(Jb, ln_w, ln_b, Jn, 1, 0);
  gemm(0, Jn, out_w, out_b, nullptr, (float*)d_out, MM, DD, DD, 1, 0, 0, 1, 0, 0, nullptr, 0, 0, 1, 0, 0, 0);
}

// Round 4
// 2327.635 us; speedup vs baseline: 2.3142x; 2.3142x over previous
//
#include <hip/hip_runtime.h>
#include <math.h>

// MFFNet forward on MI355X. Inputs/outputs fp32; GEMMs run bf16 MFMA with
// fp32 accumulation. Tile sizes chosen per-shape so every GEMM launches
// ~768 blocks (3 blocks/CU, 12 waves/CU). Heavy weights pre-converted to
// bf16; XCD-partition block swizzle; LDS row stride 72 (bank-conflict-free
// fragment reads). Workspace ~152 MB.

typedef unsigned short u16;                                 // raw bf16 storage
typedef __attribute__((ext_vector_type(8))) short short8;   // 8 bf16 = 4 VGPRs
typedef __attribute__((ext_vector_type(4))) float floatx4;

#define DD 768
#define TT 512
#define BB 8
#define MM 4096      // B*T rows
#define FFN 3072

__device__ __forceinline__ float b2f(u16 u) {
  union { unsigned u32; float f; } x; x.u32 = ((unsigned)u) << 16; return x.f;
}
__device__ __forceinline__ u16 f2b(float f) {   // round-to-nearest-even
  union { float f; unsigned u; } x; x.f = f;
  unsigned r = x.u + 0x7FFFu + ((x.u >> 16) & 1u);
  return (u16)(r >> 16);
}

// ---------------------------------------------------------------------------
// Universal GEMM: C[M,N] = act(A[M,K] @ W[N,K]^T + bias + resid) [*rowScale]
// BM/BN tile template; 4 waves/block; BK=64; LDS row stride 72 (+16B pad).
// M % BM == 0 and N % BN == 0 are required (true for all call sites).
// ---------------------------------------------------------------------------
template<int BM, int BN, int OP>
__global__ __launch_bounds__(256)
void gemm_bt(const void* __restrict__ Av, const void* __restrict__ Wv,
             const float* __restrict__ bias, const void* __restrict__ residv,
             void* __restrict__ Cv,
             int M, int N, int K,
             int aBf16, int wBf16, int rBf16, int outBf16,
             int ntaps, int pad, long wtapStride,
             const float* __restrict__ rowScale, int rsStride, int accum,
             long aBatch, long wBatch, long cBatch)
{
  constexpr int SK = 72;                       // padded LDS K-stride (u16)
  __shared__ __align__(16) u16 sA[BM * SK];
  __shared__ __align__(16) u16 sB[BN * SK];
  const int tid  = threadIdx.x;
  const int lane = tid & 63;
  const int wv   = tid >> 6;

  // XCD-partition swizzle: HW round-robins consecutive blocks over 8 XCDs;
  // invert so each XCD owns a contiguous x-major tile range (A-panel reuse).
  int gx = gridDim.x, gy = gridDim.y;
  int bn = blockIdx.y * gx + blockIdx.x;
  int Tt = gx * gy;
  if ((Tt & 7) == 0) bn = (bn & 7) * (Tt >> 3) + (bn >> 3);
  const int m0 = (bn / gx) * BM;
  const int n0 = (bn % gx) * BN;

  constexpr int NI = (BM == 128 && BN == 128) ? 4 : (BM == 128 ? 2 : 1);
  constexpr int NJ = 4;
  int wr, wc;
  if constexpr (BM == 128 && BN == 128) { wr = (wv >> 1) * 64; wc = (wv & 1) * 64; }
  else if constexpr (BM == 128)          { wr = wv * 32;        wc = 0; }
  else                                    { wr = wv * 16;        wc = 0; }

  floatx4 acc[NI][NJ];
#pragma unroll
  for (int i = 0; i < NI; ++i)
#pragma unroll
    for (int j = 0; j < NJ; ++j) acc[i][j] = (floatx4){0.f, 0.f, 0.f, 0.f};

  const int mrow = lane & 15;
  const int ksub = (lane >> 4) * 8;

  for (int tap = 0; tap < ntaps; ++tap) {
    const int dt = tap - pad;
    for (int k0 = 0; k0 < K; k0 += 64) {
      // ---- stage A tile BMx64 ----
      if (aBf16) {
        const u16* Ab = (const u16*)Av + (long)blockIdx.z * aBatch;
#pragma unroll
        for (int it = 0; it < BM / 32; ++it) {          // BM*8/256 chunks
          int slot = it * 256 + tid;
          int row = slot >> 3, col = (slot & 7) * 8;
          int gr = m0 + row;
          int t  = gr & (TT - 1);
          uint4 v = make_uint4(0u, 0u, 0u, 0u);
          if ((unsigned)(t + dt) < (unsigned)TT)
            v = *(const uint4*)(Ab + (long)(gr + dt) * K + k0 + col);
          *(uint4*)(sA + row * SK + col) = v;
        }
      } else {
        const float* Af = (const float*)Av + (long)blockIdx.z * aBatch;
#pragma unroll
        for (int it = 0; it < BM / 16; ++it) {          // BM*16/256 chunks
          int slot = it * 256 + tid;
          int row = slot >> 4, col = (slot & 15) * 4;
          int gr = m0 + row;
          int t  = gr & (TT - 1);
          float4 v = make_float4(0.f, 0.f, 0.f, 0.f);
          if ((unsigned)(t + dt) < (unsigned)TT)
            v = *(const float4*)(Af + (long)(gr + dt) * K + k0 + col);
          ushort4 h; h.x = f2b(v.x); h.y = f2b(v.y); h.z = f2b(v.z); h.w = f2b(v.w);
          *(ushort4*)(sA + row * SK + col) = h;
        }
      }
      // ---- stage W tile BNx64 ----
      if (wBf16) {
        const u16* Wb = (const u16*)Wv + (long)blockIdx.z * wBatch + (long)tap * wtapStride;
#pragma unroll
        for (int it = 0; it < BN / 32; ++it) {
          int slot = it * 256 + tid;
          int row = slot >> 3, col = (slot & 7) * 8;
          uint4 v = *(const uint4*)(Wb + (long)(n0 + row) * K + k0 + col);
          *(uint4*)(sB + row * SK + col) = v;
        }
      } else {
        const float* Wb = (const float*)Wv + (long)blockIdx.z * wBatch + (long)tap * wtapStride;
#pragma unroll
        for (int it = 0; it < BN / 16; ++it) {
          int slot = it * 256 + tid;
          int row = slot >> 4, col = (slot & 15) * 4;
          float4 v = *(const float4*)(Wb + (long)(n0 + row) * K + k0 + col);
          ushort4 h; h.x = f2b(v.x); h.y = f2b(v.y); h.z = f2b(v.z); h.w = f2b(v.w);
          *(ushort4*)(sB + row * SK + col) = h;
        }
      }
      __syncthreads();
#pragma unroll
      for (int kb = 0; kb < 64; kb += 32) {
        short8 af[NI], bfr[NJ];
#pragma unroll
        for (int i = 0; i < NI; ++i)
          af[i] = *(const short8*)(sA + (wr + i * 16 + mrow) * SK + kb + ksub);
#pragma unroll
        for (int j = 0; j < NJ; ++j)
          bfr[j] = *(const short8*)(sB + (wc + j * 16 + mrow) * SK + kb + ksub);
#pragma unroll
        for (int i = 0; i < NI; ++i)
#pragma unroll
          for (int j = 0; j < NJ; ++j)
            acc[i][j] = __builtin_amdgcn_mfma_f32_16x16x32_bf16(af[i], bfr[j], acc[i][j], 0, 0, 0);
      }
      __syncthreads();
    }
  }

  // epilogue: C/D layout col=lane&15, row=(lane>>4)*4+reg (m89-verified)
  const int cn = lane & 15;
  const int rq = (lane >> 4) * 4;
  u16*   Ch = (u16*)Cv   + (long)blockIdx.z * cBatch;
  float* Cf = (float*)Cv + (long)blockIdx.z * cBatch;
#pragma unroll
  for (int j = 0; j < NJ; ++j) {
    int gn = n0 + wc + j * 16 + cn;
    float bv = bias ? bias[gn] : 0.f;
#pragma unroll
    for (int i = 0; i < NI; ++i) {
#pragma unroll
      for (int r = 0; r < 4; ++r) {
        int gm = m0 + wr + i * 16 + rq + r;
        long idx = (long)gm * N + gn;
        float v = acc[i][j][r] + bv;
        if (residv)
          v += rBf16 ? b2f(((const u16*)residv)[idx]) : ((const float*)residv)[idx];
        if (OP == 1) v = fmaxf(v, 0.f);
        if (OP == 2) v = 0.5f * v * (1.f + erff(v * 0.70710678118654752440f));
        if (OP == 3) v = 1.f / (1.f + expf(-v));
        if (rowScale) v *= rowScale[(gm >> 9) * rsStride];
        if (outBf16) Ch[idx] = f2b(v);
        else if (accum) Cf[idx] += v;
        else Cf[idx] = v;
      }
    }
  }
  (void)M;
}

// ---------------------------------------------------------------------------
// LayerNorm over D=768; input fp32 or bf16; dual optional outputs.
// accum applies to y16 (bf16 read-modify-write) or y32.
// ---------------------------------------------------------------------------
__global__ void ln_kernel(const void* __restrict__ x, int xBf16,
                          const float* __restrict__ w, const float* __restrict__ b,
                          float* __restrict__ y32, u16* __restrict__ y16, int accum)
{
  const int row = blockIdx.x;
  const int tid = threadIdx.x;
  __shared__ float rs[256], rq[256];
  float v[3];
  long base = (long)row * DD;
  float s = 0.f, q = 0.f;
#pragma unroll
  for (int i = 0; i < 3; ++i) {
    int c = tid + i * 256;
    float t = xBf16 ? b2f(((const u16*)x)[base + c]) : ((const float*)x)[base + c];
    v[i] = t; s += t; q += t * t;
  }
  rs[tid] = s; rq[tid] = q; __syncthreads();
  for (int st = 128; st > 0; st >>= 1) {
    if (tid < st) { rs[tid] += rs[tid + st]; rq[tid] += rq[tid + st]; }
    __syncthreads();
  }
  float mean = rs[0] * (1.f / DD);
  float var  = fmaxf(rq[0] * (1.f / DD) - mean * mean, 0.f);
  float rstd = rsqrtf(var + 1e-12f);
#pragma unroll
  for (int i = 0; i < 3; ++i) {
    int c = tid + i * 256;
    float o = ((v[i] - mean) * rstd) * w[c] + b[c];
    if (y32) { if (accum) y32[base + c] += o; else y32[base + c] = o; }
    if (y16) {
      if (accum && !y32) y16[base + c] = f2b(b2f(y16[base + c]) + o);
      else y16[base + c] = f2b(o);
    }
  }
}

// rm[b][d] = mean over T of f[b,t,d]
__global__ void rowmean_kernel(const float* __restrict__ f, float* __restrict__ rm)
{
  int b = blockIdx.x / 3, chunk = blockIdx.x % 3;
  int d = chunk * 256 + threadIdx.x;
  const float* base = f + (long)b * TT * DD + d;
  float s = 0.f;
  for (int t = 0; t < TT; ++t) s += base[(long)t * DD];
  rm[b * DD + d] = s * (1.f / TT);
}

// cs[n][e] = sum over d of align_w[n][d][e]
__global__ void colsum_kernel(const float* __restrict__ w, float* __restrict__ cs)
{
  int n = blockIdx.x / 3, chunk = blockIdx.x % 3;
  int e = chunk * 256 + threadIdx.x;
  const float* base = w + (long)n * DD * DD + e;
  float s = 0.f;
  for (int d = 0; d < DD; ++d) s += base[(long)d * DD];
  cs[n * DD + e] = s;
}

// analytic per-(b,n) means -> fusion weights (+1/6 for the H.mean term)
__global__ void fusion_weights(const float* __restrict__ rm, const float* __restrict__ cs,
                               const float* __restrict__ align_b,
                               const float* __restrict__ aw, const float* __restrict__ ab,
                               float* __restrict__ wplus)
{
  __shared__ float msh[48];
  int tid = threadIdx.x;
  if (tid < 48) {
    int b = tid / 6, n = tid % 6;
    const float* r = rm + ((long)n * BB + b) * DD;
    const float* c = cs + n * DD;
    float dot = 0.f, bs = 0.f;
    for (int e = 0; e < DD; ++e) dot += r[e] * c[e];
    for (int d = 0; d < DD; ++d) bs += align_b[n * DD + d];
    msh[b * 6 + n] = (dot + bs) * (1.f / DD);
  }
  __syncthreads();
  if (tid < BB) {
    int b = tid;
    float z[6];
#pragma unroll
    for (int n = 0; n < 6; ++n) {
      float s = ab[n];
#pragma unroll
      for (int j = 0; j < 6; ++j)
        s += (aw[n * 12 + j] + aw[n * 12 + 6 + j]) * msh[b * 6 + j];
      z[n] = fmaxf(s, 0.f);
    }
    float mx = z[0];
#pragma unroll
    for (int n = 1; n < 6; ++n) mx = fmaxf(mx, z[n]);
    float se = 0.f, e[6];
#pragma unroll
    for (int n = 0; n < 6; ++n) { e[n] = expf(z[n] - mx); se += e[n]; }
#pragma unroll
    for (int n = 0; n < 6; ++n) wplus[b * 6 + n] = e[n] / se + (1.f / 6.f);
  }
}

// cc = [Et | Ea] row-wise, fp32 -> bf16
__global__ void concat_kernel(const float* __restrict__ Et, const float* __restrict__ Ea,
                              u16* __restrict__ cc)
{
  long e = (long)blockIdx.x * 256 + threadIdx.x;
  if (e >= (long)MM * 1536) return;
  int c = (int)(e % 1536);
  long r = e / 1536;
  float v = (c < 768) ? Et[r * 768 + c] : Ea[r * 768 + c - 768];
  cc[e] = f2b(v);
}

// Ef = g*Ea + (1-g)*Et, in place over Et (g is bf16)
__global__ void ef_kernel(const u16* __restrict__ g, const float* __restrict__ Ea,
                          float* __restrict__ EtEf)
{
  long e = (long)blockIdx.x * 256 + threadIdx.x;
  if (e >= (long)MM * DD) return;
  float gv = b2f(g[e]);
  EtEf[e] = gv * Ea[e] + (1.f - gv) * EtEf[e];
}

// conv weight [O,I,KT] fp32 -> [KT][O][I] bf16
__global__ void repack_conv(const float* __restrict__ src, u16* __restrict__ dst, int KT)
{
  long e = (long)blockIdx.x * 256 + threadIdx.x;
  if (e >= (long)KT * DD * DD) return;
  int k = (int)(e / (DD * DD));
  int rem = (int)(e - (long)k * DD * DD);
  int o = rem / DD, i = rem % DD;
  dst[e] = f2b(src[((long)o * DD + i) * KT + k]);
}

// convert 6 equal-size (2359296-el) fp32 weights to bf16 cache (vectorized)
__global__ void wconv6(const float* s0, const float* s1, const float* s2,
                       const float* s3, const float* s4, const float* s5,
                       u16* __restrict__ dst)
{
  long e4 = (long)blockIdx.x * 256 + threadIdx.x;   // float4 index
  int seg = (int)(e4 / 589824);
  long off = e4 - (long)seg * 589824;
  const float* ss[6] = {s0, s1, s2, s3, s4, s5};
  float4 v = *(const float4*)(ss[seg] + off * 4);
  ushort4 h; h.x = f2b(v.x); h.y = f2b(v.y); h.z = f2b(v.z); h.w = f2b(v.w);
  *(ushort4*)(dst + (long)seg * 2359296 + off * 4) = h;
}

// out[row,h] = (X[row,:] . Wt[h,:] + bias[h]) * scale ; H=12, X bf16
__global__ void lin_small(const u16* __restrict__ X, const float* __restrict__ Wt,
                          const float* __restrict__ bias, float scale,
                          float* __restrict__ out)
{
  int row = blockIdx.x * 4 + (threadIdx.x >> 6);
  int lane = threadIdx.x & 63;
  float acc[12];
#pragma unroll
  for (int h = 0; h < 12; ++h) acc[h] = 0.f;
  for (int k = lane; k < DD; k += 64) {
    float xv = b2f(X[(long)row * DD + k]);
#pragma unroll
    for (int h = 0; h < 12; ++h) acc[h] += xv * Wt[h * DD + k];
  }
#pragma unroll
  for (int h = 0; h < 12; ++h)
    for (int off = 32; off > 0; off >>= 1) acc[h] += __shfl_down(acc[h], off);
  if (lane == 0) {
#pragma unroll
    for (int h = 0; h < 12; ++h)
      out[(long)row * 12 + h] = (acc[h] + bias[h]) * scale;
  }
}

// scores over h=12, softmax over c=512 -> aw (bf16)
__global__ void scores_softmax(const float* __restrict__ qs, const float* __restrict__ ks,
                               u16* __restrict__ aw)
{
  int bs = blockIdx.x;            // b*512+s
  int b = bs >> 9;
  int tid = threadIdx.x;
  __shared__ float qsh[12];
  __shared__ float red[256];
  if (tid < 12) qsh[tid] = qs[(long)bs * 12 + tid];
  __syncthreads();
  float sc[2];
#pragma unroll
  for (int p = 0; p < 2; ++p) {
    int c = tid + p * 256;
    const float* kr = ks + (long)(b * 512 + c) * 12;
    float v = 0.f;
#pragma unroll
    for (int h = 0; h < 12; ++h) v += qsh[h] * kr[h];
    sc[p] = v;
  }
  red[tid] = fmaxf(sc[0], sc[1]); __syncthreads();
  for (int st = 128; st > 0; st >>= 1) {
    if (tid < st) red[tid] = fmaxf(red[tid], red[tid + st]);
    __syncthreads();
  }
  float mx = red[0]; __syncthreads();
  float e0 = expf(sc[0] - mx), e1 = expf(sc[1] - mx);
  red[tid] = e0 + e1; __syncthreads();
  for (int st = 128; st > 0; st >>= 1) {
    if (tid < st) red[tid] += red[tid + st];
    __syncthreads();
  }
  float inv = 1.f / red[0];
  aw[(long)bs * 512 + tid]       = f2b(e0 * inv);
  aw[(long)bs * 512 + tid + 256] = f2b(e1 * inv);
}

// per-b transpose kk[b] [512,768] bf16 -> kkT[b] [768,512] bf16
__global__ void transpose_kernel(const u16* __restrict__ in, u16* __restrict__ out)
{
  int b = blockIdx.z;
  const u16* ib = in + (long)b * TT * DD;
  u16* ob = out + (long)b * TT * DD;
  __shared__ u16 tile[32][33];
  int c0 = blockIdx.x * 32;   // d
  int r0 = blockIdx.y * 32;   // t
  int tx = threadIdx.x, ty = threadIdx.y;
#pragma unroll
  for (int i = 0; i < 4; ++i)
    tile[ty + 8 * i][tx] = ib[(long)(r0 + ty + 8 * i) * DD + c0 + tx];
  __syncthreads();
#pragma unroll
  for (int i = 0; i < 4; ++i)
    ob[(long)(c0 + ty + 8 * i) * TT + r0 + tx] = tile[tx][ty + 8 * i];
}

// ---------------------------------------------------------------------------
extern "C" void kernel_launch(void* const* d_in, const int* in_sizes, int n_in,
                              void* d_out, int out_size, void* d_ws, size_t ws_size,
                              hipStream_t stream)
{
  (void)in_sizes; (void)n_in; (void)out_size; (void)ws_size;
  const float* f[6];
  for (int i = 0; i < 6; ++i) f[i] = (const float*)d_in[i];
  const float* Ea      = (const float*)d_in[6];
  const float* align_w = (const float*)d_in[7];
  const float* align_b = (const float*)d_in[8];
  const float* att_w   = (const float*)d_in[9];
  const float* att_b   = (const float*)d_in[10];
  const float* g1_w = (const float*)d_in[11]; const float* g1_b = (const float*)d_in[12];
  const float* g2_w = (const float*)d_in[13]; const float* g2_b = (const float*)d_in[14];
  const float* g3_w = (const float*)d_in[15]; const float* g3_b = (const float*)d_in[16];
  const float* g4_w = (const float*)d_in[17]; const float* g4_b = (const float*)d_in[18];
  const float* ln_w = (const float*)d_in[19]; const float* ln_b = (const float*)d_in[20];
  const float* c1_w = (const float*)d_in[21]; const float* c1_b = (const float*)d_in[22];
  const float* c3_w = (const float*)d_in[23]; const float* c3_b = (const float*)d_in[24];
  const float* c5_w = (const float*)d_in[25]; const float* c5_b = (const float*)d_in[26];
  const float* q_w  = (const float*)d_in[27]; const float* q_b  = (const float*)d_in[28];
  const float* qa_w = (const float*)d_in[29]; const float* qa_b = (const float*)d_in[30];
  const float* k_w  = (const float*)d_in[31]; const float* k_b  = (const float*)d_in[32];
  const float* ka_w = (const float*)d_in[33]; const float* ka_b = (const float*)d_in[34];
  const float* tr_w = (const float*)d_in[35]; const float* tr_b = (const float*)d_in[36];
  const float* ao_w = (const float*)d_in[37]; const float* ao_b = (const float*)d_in[38];
  const float* fln_w = (const float*)d_in[39]; const float* fln_b = (const float*)d_in[40];
  const float* fi_w = (const float*)d_in[41]; const float* fi_b = (const float*)d_in[42];
  const float* fo_w = (const float*)d_in[43]; const float* fo_b = (const float*)d_in[44];
  const float* m1_w = (const float*)d_in[45]; const float* m1_b = (const float*)d_in[46];
  const float* m2_w = (const float*)d_in[47]; const float* m2_b = (const float*)d_in[48];
  const float* out_w = (const float*)d_in[49]; const float* out_b = (const float*)d_in[50];

  char* ws = (char*)d_ws;
  size_t off = 0;
  auto alloc = [&](size_t bytes) -> char* {
    char* p = ws + off;
    off += bytes;
    off = (off + 255) & ~(size_t)255;
    return p;
  };
  const long MD = (long)MM * DD;        // 3,145,728 elements

  // small scratch
  float* rmb   = (float*)alloc(6L * BB * DD * 4);
  float* csb   = (float*)alloc(6L * DD * 4);
  float* wplus = (float*)alloc(48 * 4);
  float* qsf   = (float*)alloc((long)MM * 12 * 4);
  float* ksf   = (float*)alloc((long)MM * 12 * 4);

  // bf16 weight cache: [g1|g2|fi|fo|m1|m2] (6 x 2359296) + w3r + w5r
  u16* Wc = (u16*)alloc((6L * 2359296 + 1769472 + 2949120) * 2);   // 37.75 MB
  u16* cW_g1 = Wc;
  u16* cW_g2 = Wc + 2359296L;
  u16* cW_fi = Wc + 4718592L;
  u16* cW_fo = Wc + 7077888L;
  u16* cW_m1 = Wc + 9437184L;
  u16* cW_m2 = Wc + 11796480L;
  u16* w3r   = Wc + 14155776L;
  u16* w5r   = Wc + 15925248L;

  // big aliased regions
  char* R1 = alloc(2 * MD * 4);     // 25.17 MB: gated cc/o1/o2 -> ff temps -> Pn/Jn
  char* R2 = alloc(MD * 4);         // 12.58 MB: Et(f32) -> attp(b16)+outp(b16)
  char* R3 = alloc(MD * 4);         // 12.58 MB: o3(b16)+g(b16) -> attb(b16)+Pacc(b16)
  char* R4 = alloc(MD * 4);         // 12.58 MB: xb32 (f32, live to end)
  char* R5 = alloc(MD * 2);         //  6.29 MB: xb16
  char* R6 = alloc(3 * MD * 2);     // 18.87 MB: U1,U3,U5(b16) -> Jb(f32)
  char* R8 = alloc((long)MM * FFN * 2); // 25.17 MB: interb(b16)
  // total ~152 MB

  u16*   cc    = (u16*)R1;                    // M x 1536
  u16*   o1    = (u16*)(R1 + MD * 2);         // M x 1536 (second half)
  u16*   o2    = (u16*)R1;                    // reuses cc slot after g1
  u16*   qbuf  = (u16*)R1;                    // fastformer slots
  u16*   ctxkk = (u16*)R1 + MD;               // kk16 then ctxl
  u16*   kkTsf = (u16*)(R1 + MD * 2);         // kkT then selfb
  u16*   awb   = (u16*)(R1 + MD * 2) + MD;    // 2,097,152 els <= MD
  u16*   Pn    = (u16*)R1;
  u16*   Jn    = (u16*)R1 + MD;
  float* Et    = (float*)R2;
  u16*   attp  = (u16*)R2;
  u16*   outp  = (u16*)R2 + MD;
  u16*   o3    = (u16*)R3;
  u16*   gb    = (u16*)R3 + MD;
  u16*   attb  = (u16*)R3;
  u16*   Pacc  = (u16*)R3 + MD;
  float* xb32  = (float*)R4;
  u16*   xb16  = (u16*)R5;
  u16*   U1    = (u16*)R6;
  u16*   U3    = (u16*)R6 + MD;
  u16*   U5    = (u16*)R6 + 2 * MD;
  float* Jb    = (float*)R6;
  u16*   interb = (u16*)R8;

  // tile: 0=(64,64) 1=(128,64) 2=(128,128)
  auto gemm = [&](int tile, int op, const void* A, const void* W, const float* bias,
                  const void* resid, void* Cc, int Mi, int Ni, int Ki,
                  int aB, int wB, int rB, int oB,
                  int ntaps, int pad, long wtap,
                  const float* rsc, int rss, int acc,
                  int batch, long ab, long wb, long cb) {
#define GL(BM, BN, OPV) gemm_bt<BM, BN, OPV><<<dim3(Ni / BN, Mi / BM, batch), 256, 0, stream>>>( \
      A, W, bias, resid, Cc, Mi, Ni, Ki, aB, wB, rB, oB, ntaps, pad, wtap, rsc, rss, acc, ab, wb, cb)
    if (tile == 0) {
      if (op == 0) GL(64, 64, 0); else if (op == 1) GL(64, 64, 1);
      else if (op == 2) GL(64, 64, 2); else GL(64, 64, 3);
    } else if (tile == 1) {
      if (op == 0) GL(128, 64, 0); else if (op == 1) GL(128, 64, 1);
      else if (op == 2) GL(128, 64, 2); else GL(128, 64, 3);
    } else {
      if (op == 0) GL(128, 128, 0); else if (op == 1) GL(128, 128, 1);
      else if (op == 2) GL(128, 128, 2); else GL(128, 128, 3);
    }
#undef GL
  };
  const int EW  = (int)((MD + 255) / 256);
  const int EW2 = (int)((MD * 2 + 255) / 256);

  // --- weight conversion pre-pass ---
  wconv6<<<13824, 256, 0, stream>>>(g1_w, g2_w, fi_w, fo_w, m1_w, m2_w, Wc);
  repack_conv<<<(3 * 589824 + 255) / 256, 256, 0, stream>>>(c3_w, w3r, 3);
  repack_conv<<<(5 * 589824 + 255) / 256, 256, 0, stream>>>(c5_w, w5r, 5);

  // --- fusion weights (analytic means) ---
  for (int n = 0; n < 6; ++n)
    rowmean_kernel<<<24, 256, 0, stream>>>(f[n], rmb + (long)n * BB * DD);
  colsum_kernel<<<18, 256, 0, stream>>>(align_w, csb);
  fusion_weights<<<1, 64, 0, stream>>>(rmb, csb, align_b, att_w, att_b, wplus);

  // --- FeatureAlignment accumulated into Et with per-(b,n) row scales ---
  for (int n = 0; n < 6; ++n)
    gemm(0, 0, f[n], align_w + (long)n * DD * DD, align_b + n * DD, nullptr, Et,
         MM, DD, DD, 0, 0, 0, 0, 1, 0, 0, wplus + n, 6, (n > 0) ? 1 : 0, 1, 0, 0, 0);

  // --- GatedFusion ---
  concat_kernel<<<EW2, 256, 0, stream>>>(Et, Ea, cc);
  gemm(1, 1, cc, cW_g1, g1_b, nullptr, o1, MM, 1536, 1536, 1, 1, 0, 1, 1, 0, 0, nullptr, 0, 0, 1, 0, 0, 0);
  gemm(1, 1, o1, cW_g2, g2_b, nullptr, o2, MM, 1536, 1536, 1, 1, 0, 1, 1, 0, 0, nullptr, 0, 0, 1, 0, 0, 0);
  gemm(0, 1, o2, g3_w, g3_b, nullptr, o3, MM, DD, 1536, 1, 0, 0, 1, 1, 0, 0, nullptr, 0, 0, 1, 0, 0, 0);
  gemm(0, 3, o3, g4_w, g4_b, nullptr, gb, MM, DD, DD, 1, 0, 0, 1, 1, 0, 0, nullptr, 0, 0, 1, 0, 0, 0);
  ef_kernel<<<EW, 256, 0, stream>>>(gb, Ea, Et);          // Ef in place

  // --- MSFastformer front ---
  ln_kernel<<<MM, 256, 0, stream>>>(Et, 0, ln_w, ln_b, xb32, xb16, 0);   // x (dual)
  gemm(0, 0, xb16, c1_w, c1_b, nullptr, U1, MM, DD, DD, 1, 0, 0, 1, 1, 0, 0, nullptr, 0, 0, 1, 0, 0, 0);
  gemm(0, 0, xb16, w3r, c3_b, nullptr, U3, MM, DD, DD, 1, 1, 0, 1, 3, 1, 589824, nullptr, 0, 0, 1, 0, 0, 0);
  gemm(0, 0, xb16, w5r, c5_b, nullptr, U5, MM, DD, DD, 1, 1, 0, 1, 5, 2, 589824, nullptr, 0, 0, 1, 0, 0, 0);

  // --- fastformer layers (shared weights); P accumulated (bf16) ---
  auto fastformer = [&](const u16* hid, const u16* ctx, int layer) {
    gemm(0, 0, hid, q_w, q_b, nullptr, qbuf, MM, DD, DD, 1, 0, 0, 1, 1, 0, 0, nullptr, 0, 0, 1, 0, 0, 0);
    gemm(0, 0, ctx, k_w, k_b, nullptr, ctxkk, MM, DD, DD, 1, 0, 0, 1, 1, 0, 0, nullptr, 0, 0, 1, 0, 0, 0);
    lin_small<<<MM / 4, 256, 0, stream>>>(qbuf, qa_w, qa_b, 0.125f, qsf);
    lin_small<<<MM / 4, 256, 0, stream>>>(ctxkk, ka_w, ka_b, 0.125f, ksf);
    scores_softmax<<<MM, 256, 0, stream>>>(qsf, ksf, awb);
    transpose_kernel<<<dim3(24, 16, 8), dim3(32, 8), 0, stream>>>(ctxkk, kkTsf);
    // ctx_layer = aw @ kkT^T  (batched over b; 12x8x8 = 768 blocks)
    gemm(0, 0, awb, kkTsf, nullptr, nullptr, ctxkk, TT, DD, TT, 1, 1, 0, 1, 1, 0, 0, nullptr, 0, 0,
         BB, (long)TT * TT, (long)DD * TT, (long)TT * DD);
    gemm(0, 0, ctxkk, tr_w, tr_b, qbuf, kkTsf, MM, DD, DD, 1, 0, 1, 1, 1, 0, 0, nullptr, 0, 0, 1, 0, 0, 0);
    gemm(0, 0, kkTsf, ao_w, ao_b, hid, attp, MM, DD, DD, 1, 0, 1, 1, 1, 0, 0, nullptr, 0, 0, 1, 0, 0, 0);
    ln_kernel<<<MM, 256, 0, stream>>>(attp, 1, fln_w, fln_b, nullptr, attb, 0);
    gemm(2, 2, attb, cW_fi, fi_b, nullptr, interb, MM, FFN, DD, 1, 1, 0, 1, 1, 0, 0, nullptr, 0, 0, 1, 0, 0, 0);
    gemm(0, 0, interb, cW_fo, fo_b, attb, outp, MM, DD, FFN, 1, 1, 1, 1, 1, 0, 0, nullptr, 0, 0, 1, 0, 0, 0);
    ln_kernel<<<MM, 256, 0, stream>>>(outp, 1, fln_w, fln_b, nullptr, Pacc, (layer > 0) ? 1 : 0);
  };
  fastformer(U5, U3, 0);
  fastformer(U3, U1, 1);
  fastformer(U1, U5, 2);

  // --- tail ---
  ln_kernel<<<MM, 256, 0, stream>>>(Pacc, 1, ln_w, ln_b, nullptr, Pn, 0);
  gemm(2, 2, Pn, cW_m1, m1_b, nullptr, interb, MM, FFN, DD, 1, 1, 0, 1, 1, 0, 0, nullptr, 0, 0, 1, 0, 0, 0);
  gemm(0, 0, interb, cW_m2, m2_b, xb32, Jb, MM, DD, FFN, 1, 1, 0, 0, 1, 0, 0, nullptr, 0, 0, 1, 0, 0, 0);
  ln_kernel<<<MM, 256, 0, stream>>>(Jb, 0, ln_w, ln_b, nullptr, Jn, 0);
  gemm(0, 0, Jn, out_w, out_b, nullptr, (float*)d_out, MM, DD, DD, 1, 0, 0, 0, 1, 0, 0, nullptr, 0, 0, 1, 0, 0, 0);
}

// Round 5
// 1822.925 us; speedup vs baseline: 2.9550x; 1.2769x over previous
//
#include <hip/hip_runtime.h>
#include <math.h>

// MFFNet forward on MI355X. fp32 in/out; all GEMMs bf16-MFMA with fp32 acc.
// m97-structure GEMM core: global_load_lds width-16 async staging, SK=64,
// single LDS buffer, 2 barriers per k-step. All GEMM operands pre-converted
// to a bf16 cache in one pass. Workspace ~157 MB.

typedef unsigned short u16;                                 // raw bf16 storage
typedef __attribute__((ext_vector_type(8))) short short8;   // 8 bf16 = 4 VGPRs
typedef __attribute__((ext_vector_type(4))) float floatx4;
typedef unsigned __attribute__((address_space(1))) gu32;
typedef unsigned __attribute__((address_space(3))) lu32;

#define DD 768
#define TT 512
#define BB 8
#define MM 4096      // B*T rows
#define FFN 3072

__device__ __forceinline__ float b2f(u16 u) {
  union { unsigned u32; float f; } x; x.u32 = ((unsigned)u) << 16; return x.f;
}
__device__ __forceinline__ u16 f2b(float f) {   // round-to-nearest-even
  union { float f; unsigned u; } x; x.f = f;
  unsigned r = x.u + 0x7FFFu + ((x.u >> 16) & 1u);
  return (u16)(r >> 16);
}

// ---------------------------------------------------------------------------
// GEMM: C[M,N] = act(A[M,K] @ W[N,K]^T + bias + resid) [*rowScale]
// A, W are bf16. BM/BN tile; 4 waves; BK=64; LDS stride 64 (global_load_lds
// requires contiguous lane*16 dest). ntaps/pad = conv-over-T (zero page for
// OOB rows). OP: 0=none 1=relu 2=gelu 3=sigmoid.
// ---------------------------------------------------------------------------
template<int BM, int BN, int OP>
__global__ __launch_bounds__(256)
void gemm_bt(const u16* __restrict__ A, const u16* __restrict__ W,
             const float* __restrict__ bias, const void* __restrict__ residv,
             void* __restrict__ Cv, int N, int K,
             int rBf16, int outBf16,
             int ntaps, int pad, long wtapStride,
             const float* __restrict__ rowScale, int rsStride, int accum,
             long aBatch, long wBatch, long cBatch,
             const u16* __restrict__ zp)
{
  __shared__ __align__(16) u16 sA[BM * 64];
  __shared__ __align__(16) u16 sB[BN * 64];
  const int tid  = threadIdx.x;
  const int lane = tid & 63;
  const int wv   = tid >> 6;

  // XCD swizzle: contiguous tile range per XCD
  int gx = gridDim.x, gy = gridDim.y;
  int bn = blockIdx.y * gx + blockIdx.x;
  int Tt = gx * gy;
  if ((Tt & 7) == 0) bn = (bn & 7) * (Tt >> 3) + (bn >> 3);
  const int m0 = (bn / gx) * BM;
  const int n0 = (bn % gx) * BN;
  const u16* Ab  = A + (long)blockIdx.z * aBatch;
  const u16* Wb0 = W + (long)blockIdx.z * wBatch;

  constexpr int NI = (BM == 128 && BN == 128) ? 4 : (BM == 128 ? 2 : 1);
  constexpr int NJ = 4;
  int wr, wc;
  if constexpr (BM == 128 && BN == 128) { wr = (wv >> 1) * 64; wc = (wv & 1) * 64; }
  else if constexpr (BM == 128)          { wr = wv * 32;        wc = 0; }
  else                                    { wr = wv * 16;        wc = 0; }

  floatx4 acc[NI][NJ];
#pragma unroll
  for (int i = 0; i < NI; ++i)
#pragma unroll
    for (int j = 0; j < NJ; ++j) acc[i][j] = (floatx4){0.f, 0.f, 0.f, 0.f};

  const int mrow = lane & 15;
  const int ksub = (lane >> 4) * 8;

  for (int tap = 0; tap < ntaps; ++tap) {
    const int dt = tap - pad;
    const u16* Wt = Wb0 + (long)tap * wtapStride;
    for (int k0 = 0; k0 < K; k0 += 64) {
      // async DMA stage A tile BMx64: lane-contiguous 16B chunks
#pragma unroll
      for (int it = 0; it < BM / 32; ++it) {
        int slot = it * 256 + tid;
        int row = slot >> 3, col = (slot & 7) * 8;
        int gr = m0 + row;
        int t  = gr & (TT - 1);
        const u16* src = ((unsigned)(t + dt) < (unsigned)TT)
                       ? (Ab + (long)(gr + dt) * K + k0 + col) : zp;
        __builtin_amdgcn_global_load_lds((const gu32*)src,
                                         (lu32*)((char*)sA + slot * 16), 16, 0, 0);
      }
      // async DMA stage W tile BNx64
#pragma unroll
      for (int it = 0; it < BN / 32; ++it) {
        int slot = it * 256 + tid;
        int row = slot >> 3, col = (slot & 7) * 8;
        const u16* src = Wt + (long)(n0 + row) * K + k0 + col;
        __builtin_amdgcn_global_load_lds((const gu32*)src,
                                         (lu32*)((char*)sB + slot * 16), 16, 0, 0);
      }
      __syncthreads();     // drains vmcnt(0): DMA complete, LDS visible
#pragma unroll
      for (int kb = 0; kb < 64; kb += 32) {
        short8 af[NI], bfr[NJ];
#pragma unroll
        for (int i = 0; i < NI; ++i)
          af[i] = *(const short8*)(sA + (wr + i * 16 + mrow) * 64 + kb + ksub);
#pragma unroll
        for (int j = 0; j < NJ; ++j)
          bfr[j] = *(const short8*)(sB + (wc + j * 16 + mrow) * 64 + kb + ksub);
#pragma unroll
        for (int i = 0; i < NI; ++i)
#pragma unroll
          for (int j = 0; j < NJ; ++j)
            acc[i][j] = __builtin_amdgcn_mfma_f32_16x16x32_bf16(af[i], bfr[j], acc[i][j], 0, 0, 0);
      }
      __syncthreads();     // all reads done before next DMA overwrites
    }
  }

  // epilogue: C/D layout col=lane&15, row=(lane>>4)*4+reg (m89-verified)
  const int cn = lane & 15;
  const int rq = (lane >> 4) * 4;
  u16*   Ch = (u16*)Cv   + (long)blockIdx.z * cBatch;
  float* Cf = (float*)Cv + (long)blockIdx.z * cBatch;
#pragma unroll
  for (int j = 0; j < NJ; ++j) {
    int gn = n0 + wc + j * 16 + cn;
    float bv = bias ? bias[gn] : 0.f;
#pragma unroll
    for (int i = 0; i < NI; ++i) {
#pragma unroll
      for (int r = 0; r < 4; ++r) {
        int gm = m0 + wr + i * 16 + rq + r;
        long idx = (long)gm * N + gn;
        float v = acc[i][j][r] + bv;
        if (residv)
          v += rBf16 ? b2f(((const u16*)residv)[idx]) : ((const float*)residv)[idx];
        if (OP == 1) v = fmaxf(v, 0.f);
        if (OP == 2) v = 0.5f * v * (1.f + erff(v * 0.70710678118654752440f));
        if (OP == 3) v = 1.f / (1.f + expf(-v));
        if (rowScale) v *= rowScale[(gm >> 9) * rsStride];
        if (outBf16) Ch[idx] = f2b(v);
        else if (accum) Cf[idx] += v;
        else Cf[idx] = v;
      }
    }
  }
}

// ---------------------------------------------------------------------------
// bulk fp32 -> bf16 conversion, up to 21 jobs in one launch
// ---------------------------------------------------------------------------
#define NJOBS 21
struct ConvJobs {
  const float* src[NJOBS];
  u16* dst[NJOBS];
  int n4[NJOBS];           // float4 count per job
};
__global__ void convert_all(ConvJobs J, long total4)
{
  long g = (long)blockIdx.x * 256 + threadIdx.x;
  if (g >= total4) return;
  int j = 0; long off = g;
  while (off >= J.n4[j]) { off -= J.n4[j]; ++j; }
  float4 v = *(const float4*)(J.src[j] + off * 4);
  ushort4 h; h.x = f2b(v.x); h.y = f2b(v.y); h.z = f2b(v.z); h.w = f2b(v.w);
  *(ushort4*)(J.dst[j] + off * 4) = h;
}

__global__ void zero_kernel(u16* zp) { if (threadIdx.x < 128) zp[threadIdx.x] = 0; }

// LayerNorm over D=768; input fp32 or bf16; out fp32 or bf16, optional accum
__global__ void ln_kernel(const void* __restrict__ x, int xBf16,
                          const float* __restrict__ w, const float* __restrict__ b,
                          float* __restrict__ y32, u16* __restrict__ y16, int accum)
{
  const int row = blockIdx.x;
  const int tid = threadIdx.x;
  __shared__ float rs[256], rq[256];
  float v[3];
  long base = (long)row * DD;
  float s = 0.f, q = 0.f;
#pragma unroll
  for (int i = 0; i < 3; ++i) {
    int c = tid + i * 256;
    float t = xBf16 ? b2f(((const u16*)x)[base + c]) : ((const float*)x)[base + c];
    v[i] = t; s += t; q += t * t;
  }
  rs[tid] = s; rq[tid] = q; __syncthreads();
  for (int st = 128; st > 0; st >>= 1) {
    if (tid < st) { rs[tid] += rs[tid + st]; rq[tid] += rq[tid + st]; }
    __syncthreads();
  }
  float mean = rs[0] * (1.f / DD);
  float var  = fmaxf(rq[0] * (1.f / DD) - mean * mean, 0.f);
  float rstd = rsqrtf(var + 1e-12f);
#pragma unroll
  for (int i = 0; i < 3; ++i) {
    int c = tid + i * 256;
    float o = ((v[i] - mean) * rstd) * w[c] + b[c];
    if (y32) { if (accum) y32[base + c] += o; else y32[base + c] = o; }
    if (y16) {
      if (accum && !y32) y16[base + c] = f2b(b2f(y16[base + c]) + o);
      else y16[base + c] = f2b(o);
    }
  }
}

__global__ void rowmean_kernel(const float* __restrict__ f, float* __restrict__ rm)
{
  int b = blockIdx.x / 3, chunk = blockIdx.x % 3;
  int d = chunk * 256 + threadIdx.x;
  const float* base = f + (long)b * TT * DD + d;
  float s = 0.f;
  for (int t = 0; t < TT; ++t) s += base[(long)t * DD];
  rm[b * DD + d] = s * (1.f / TT);
}

__global__ void colsum_kernel(const float* __restrict__ w, float* __restrict__ cs)
{
  int n = blockIdx.x / 3, chunk = blockIdx.x % 3;
  int e = chunk * 256 + threadIdx.x;
  const float* base = w + (long)n * DD * DD + e;
  float s = 0.f;
  for (int d = 0; d < DD; ++d) s += base[(long)d * DD];
  cs[n * DD + e] = s;
}

__global__ void fusion_weights(const float* __restrict__ rm, const float* __restrict__ cs,
                               const float* __restrict__ align_b,
                               const float* __restrict__ aw, const float* __restrict__ ab,
                               float* __restrict__ wplus)
{
  __shared__ float msh[48];
  int tid = threadIdx.x;
  if (tid < 48) {
    int b = tid / 6, n = tid % 6;
    const float* r = rm + ((long)n * BB + b) * DD;
    const float* c = cs + n * DD;
    float dot = 0.f, bs = 0.f;
    for (int e = 0; e < DD; ++e) dot += r[e] * c[e];
    for (int d = 0; d < DD; ++d) bs += align_b[n * DD + d];
    msh[b * 6 + n] = (dot + bs) * (1.f / DD);
  }
  __syncthreads();
  if (tid < BB) {
    int b = tid;
    float z[6];
#pragma unroll
    for (int n = 0; n < 6; ++n) {
      float s = ab[n];
#pragma unroll
      for (int j = 0; j < 6; ++j)
        s += (aw[n * 12 + j] + aw[n * 12 + 6 + j]) * msh[b * 6 + j];
      z[n] = fmaxf(s, 0.f);
    }
    float mx = z[0];
#pragma unroll
    for (int n = 1; n < 6; ++n) mx = fmaxf(mx, z[n]);
    float se = 0.f, e[6];
#pragma unroll
    for (int n = 0; n < 6; ++n) { e[n] = expf(z[n] - mx); se += e[n]; }
#pragma unroll
    for (int n = 0; n < 6; ++n) wplus[b * 6 + n] = e[n] / se + (1.f / 6.f);
  }
}

__global__ void concat_kernel(const float* __restrict__ Et, const float* __restrict__ Ea,
                              u16* __restrict__ cc)
{
  long e = (long)blockIdx.x * 256 + threadIdx.x;
  if (e >= (long)MM * 1536) return;
  int c = (int)(e % 1536);
  long r = e / 1536;
  float v = (c < 768) ? Et[r * 768 + c] : Ea[r * 768 + c - 768];
  cc[e] = f2b(v);
}

__global__ void ef_kernel(const u16* __restrict__ g, const float* __restrict__ Ea,
                          float* __restrict__ EtEf)
{
  long e = (long)blockIdx.x * 256 + threadIdx.x;
  if (e >= (long)MM * DD) return;
  float gv = b2f(g[e]);
  EtEf[e] = gv * Ea[e] + (1.f - gv) * EtEf[e];
}

// conv weight [O,I,KT] fp32 -> [KT][O][I] bf16
__global__ void repack_conv(const float* __restrict__ src, u16* __restrict__ dst, int KT)
{
  long e = (long)blockIdx.x * 256 + threadIdx.x;
  if (e >= (long)KT * DD * DD) return;
  int k = (int)(e / (DD * DD));
  int rem = (int)(e - (long)k * DD * DD);
  int o = rem / DD, i = rem % DD;
  dst[e] = f2b(src[((long)o * DD + i) * KT + k]);
}

// out[row,h] = (X[row,:] . Wt[h,:] + bias[h]) * scale ; H=12, X bf16
__global__ void lin_small(const u16* __restrict__ X, const float* __restrict__ Wt,
                          const float* __restrict__ bias, float scale,
                          float* __restrict__ out)
{
  int row = blockIdx.x * 4 + (threadIdx.x >> 6);
  int lane = threadIdx.x & 63;
  float acc[12];
#pragma unroll
  for (int h = 0; h < 12; ++h) acc[h] = 0.f;
  for (int k = lane; k < DD; k += 64) {
    float xv = b2f(X[(long)row * DD + k]);
#pragma unroll
    for (int h = 0; h < 12; ++h) acc[h] += xv * Wt[h * DD + k];
  }
#pragma unroll
  for (int h = 0; h < 12; ++h)
    for (int off = 32; off > 0; off >>= 1) acc[h] += __shfl_down(acc[h], off);
  if (lane == 0) {
#pragma unroll
    for (int h = 0; h < 12; ++h)
      out[(long)row * 12 + h] = (acc[h] + bias[h]) * scale;
  }
}

__global__ void scores_softmax(const float* __restrict__ qs, const float* __restrict__ ks,
                               u16* __restrict__ aw)
{
  int bs = blockIdx.x;            // b*512+s
  int b = bs >> 9;
  int tid = threadIdx.x;
  __shared__ float qsh[12];
  __shared__ float red[256];
  if (tid < 12) qsh[tid] = qs[(long)bs * 12 + tid];
  __syncthreads();
  float sc[2];
#pragma unroll
  for (int p = 0; p < 2; ++p) {
    int c = tid + p * 256;
    const float* kr = ks + (long)(b * 512 + c) * 12;
    float v = 0.f;
#pragma unroll
    for (int h = 0; h < 12; ++h) v += qsh[h] * kr[h];
    sc[p] = v;
  }
  red[tid] = fmaxf(sc[0], sc[1]); __syncthreads();
  for (int st = 128; st > 0; st >>= 1) {
    if (tid < st) red[tid] = fmaxf(red[tid], red[tid + st]);
    __syncthreads();
  }
  float mx = red[0]; __syncthreads();
  float e0 = expf(sc[0] - mx), e1 = expf(sc[1] - mx);
  red[tid] = e0 + e1; __syncthreads();
  for (int st = 128; st > 0; st >>= 1) {
    if (tid < st) red[tid] += red[tid + st];
    __syncthreads();
  }
  float inv = 1.f / red[0];
  aw[(long)bs * 512 + tid]       = f2b(e0 * inv);
  aw[(long)bs * 512 + tid + 256] = f2b(e1 * inv);
}

__global__ void transpose_kernel(const u16* __restrict__ in, u16* __restrict__ out)
{
  int b = blockIdx.z;
  const u16* ib = in + (long)b * TT * DD;
  u16* ob = out + (long)b * TT * DD;
  __shared__ u16 tile[32][33];
  int c0 = blockIdx.x * 32;   // d
  int r0 = blockIdx.y * 32;   // t
  int tx = threadIdx.x, ty = threadIdx.y;
#pragma unroll
  for (int i = 0; i < 4; ++i)
    tile[ty + 8 * i][tx] = ib[(long)(r0 + ty + 8 * i) * DD + c0 + tx];
  __syncthreads();
#pragma unroll
  for (int i = 0; i < 4; ++i)
    ob[(long)(c0 + ty + 8 * i) * TT + r0 + tx] = tile[tx][ty + 8 * i];
}

// ---------------------------------------------------------------------------
extern "C" void kernel_launch(void* const* d_in, const int* in_sizes, int n_in,
                              void* d_out, int out_size, void* d_ws, size_t ws_size,
                              hipStream_t stream)
{
  (void)in_sizes; (void)n_in; (void)out_size; (void)ws_size;
  const float* f[6];
  for (int i = 0; i < 6; ++i) f[i] = (const float*)d_in[i];
  const float* Ea      = (const float*)d_in[6];
  const float* align_w = (const float*)d_in[7];
  const float* align_b = (const float*)d_in[8];
  const float* att_w   = (const float*)d_in[9];
  const float* att_b   = (const float*)d_in[10];
  const float* g1_w = (const float*)d_in[11]; const float* g1_b = (const float*)d_in[12];
  const float* g2_w = (const float*)d_in[13]; const float* g2_b = (const float*)d_in[14];
  const float* g3_w = (const float*)d_in[15]; const float* g3_b = (const float*)d_in[16];
  const float* g4_w = (const float*)d_in[17]; const float* g4_b = (const float*)d_in[18];
  const float* ln_w = (const float*)d_in[19]; const float* ln_b = (const float*)d_in[20];
  const float* c1_w = (const float*)d_in[21]; const float* c1_b = (const float*)d_in[22];
  const float* c3_w = (const float*)d_in[23]; const float* c3_b = (const float*)d_in[24];
  const float* c5_w = (const float*)d_in[25]; const float* c5_b = (const float*)d_in[26];
  const float* q_w  = (const float*)d_in[27]; const float* q_b  = (const float*)d_in[28];
  const float* qa_w = (const float*)d_in[29]; const float* qa_b = (const float*)d_in[30];
  const float* k_w  = (const float*)d_in[31]; const float* k_b  = (const float*)d_in[32];
  const float* ka_w = (const float*)d_in[33]; const float* ka_b = (const float*)d_in[34];
  const float* tr_w = (const float*)d_in[35]; const float* tr_b = (const float*)d_in[36];
  const float* ao_w = (const float*)d_in[37]; const float* ao_b = (const float*)d_in[38];
  const float* fln_w = (const float*)d_in[39]; const float* fln_b = (const float*)d_in[40];
  const float* fi_w = (const float*)d_in[41]; const float* fi_b = (const float*)d_in[42];
  const float* fo_w = (const float*)d_in[43]; const float* fo_b = (const float*)d_in[44];
  const float* m1_w = (const float*)d_in[45]; const float* m1_b = (const float*)d_in[46];
  const float* m2_w = (const float*)d_in[47]; const float* m2_b = (const float*)d_in[48];
  const float* out_w = (const float*)d_in[49]; const float* out_b = (const float*)d_in[50];

  char* ws = (char*)d_ws;
  size_t off = 0;
  auto alloc = [&](size_t bytes) -> char* {
    char* p = ws + off;
    off += bytes;
    off = (off + 255) & ~(size_t)255;
    return p;
  };
  const long MD = (long)MM * DD;        // 3,145,728 elements

  // small scratch
  u16*   zp    = (u16*)alloc(256);
  float* rmb   = (float*)alloc(6L * BB * DD * 4);
  float* csb   = (float*)alloc(6L * DD * 4);
  float* wplus = (float*)alloc(48 * 4);
  float* qsf   = (float*)alloc((long)MM * 12 * 4);
  float* ksf   = (float*)alloc((long)MM * 12 * 4);

  // bf16 weight cache (27,721,728 els = 55.4 MB)
  u16* Wc = (u16*)alloc(27721728L * 2);
  u16* cW_g1   = Wc;
  u16* cW_g2   = Wc + 2359296L;
  u16* cW_fi   = Wc + 4718592L;
  u16* cW_fo   = Wc + 7077888L;
  u16* cW_m1   = Wc + 9437184L;
  u16* cW_m2   = Wc + 11796480L;
  u16* cW_g3   = Wc + 14155776L;
  u16* cW_al   = Wc + 15335424L;
  u16* cW_g4   = Wc + 18874368L;
  u16* cW_c1   = Wc + 19464192L;
  u16* cW_q    = Wc + 20054016L;
  u16* cW_k    = Wc + 20643840L;
  u16* cW_tr   = Wc + 21233664L;
  u16* cW_ao   = Wc + 21823488L;
  u16* cW_out  = Wc + 22413312L;
  u16* w3r     = Wc + 23003136L;
  u16* w5r     = Wc + 24772608L;

  // big aliased regions
  char* R1 = alloc(2 * MD * 4);     // cc/o1/o2 -> qbuf/ctxkk/kkTsf/awb -> Pn/Jn
  char* R2 = alloc(MD * 4);         // Et(f32) -> attp(b16)+outp(b16)
  char* R3 = alloc(MD * 4);         // o3(b16)+gb(b16) -> attb(b16)+Pacc(b16)
  char* R5 = alloc(MD * 2);         // xb16
  char* R6 = alloc(3 * MD * 2);     // f16s (spills into R8) -> U1/U3/U5 -> Jb(f32)
  char* R8 = alloc((long)MM * FFN * 2); // f16s tail -> interb
  // total ~156.7 MB

  u16*   cc    = (u16*)R1;
  u16*   o1    = (u16*)(R1 + MD * 2);
  u16*   o2    = (u16*)R1;
  u16*   qbuf  = (u16*)R1;
  u16*   ctxkk = (u16*)R1 + MD;
  u16*   kkTsf = (u16*)(R1 + MD * 2);
  u16*   awb   = (u16*)(R1 + MD * 2) + MD;
  u16*   Pn    = (u16*)R1;
  u16*   Jn    = (u16*)R1 + MD;
  float* Et    = (float*)R2;
  u16*   attp  = (u16*)R2;
  u16*   outp  = (u16*)R2 + MD;
  u16*   o3    = (u16*)R3;
  u16*   gb    = (u16*)R3 + MD;
  u16*   attb  = (u16*)R3;
  u16*   Pacc  = (u16*)R3 + MD;
  u16*   xb16  = (u16*)R5;
  u16*   f16s  = (u16*)R6;          // 6*MD b16, spans R6+R8 head
  u16*   U1    = (u16*)R6;
  u16*   U3    = (u16*)R6 + MD;
  u16*   U5    = (u16*)R6 + 2 * MD;
  float* Jb    = (float*)R6;
  u16*   interb = (u16*)R8;

  auto gemm = [&](int tile, int op, const u16* A, const u16* W, const float* bias,
                  const void* resid, void* Cc, int Mi, int Ni, int Ki,
                  int rB, int oB, int ntaps, int pad, long wtap,
                  const float* rsc, int rss, int acc,
                  int batch, long ab, long wb, long cb) {
#define GL(BM, BN, OPV) gemm_bt<BM, BN, OPV><<<dim3(Ni / BN, Mi / BM, batch), 256, 0, stream>>>( \
      A, W, bias, resid, Cc, Ni, Ki, rB, oB, ntaps, pad, wtap, rsc, rss, acc, ab, wb, cb, zp)
    if (tile == 0) {
      if (op == 0) GL(64, 64, 0); else if (op == 1) GL(64, 64, 1);
      else if (op == 2) GL(64, 64, 2); else GL(64, 64, 3);
    } else if (tile == 1) {
      if (op == 0) GL(128, 64, 0); else if (op == 1) GL(128, 64, 1);
      else if (op == 2) GL(128, 64, 2); else GL(128, 64, 3);
    } else {
      if (op == 0) GL(128, 128, 0); else if (op == 1) GL(128, 128, 1);
      else if (op == 2) GL(128, 128, 2); else GL(128, 128, 3);
    }
#undef GL
  };
  const int EW  = (int)((MD + 255) / 256);
  const int EW2 = (int)((MD * 2 + 255) / 256);

  zero_kernel<<<1, 128, 0, stream>>>(zp);

  // --- bulk conversion: 15 weights + 6 f-inputs ---
  {
    ConvJobs J;
    const float* s[NJOBS] = {g1_w, g2_w, fi_w, fo_w, m1_w, m2_w, g3_w, align_w,
                             g4_w, c1_w, q_w, k_w, tr_w, ao_w, out_w,
                             f[0], f[1], f[2], f[3], f[4], f[5]};
    u16* d[NJOBS] = {cW_g1, cW_g2, cW_fi, cW_fo, cW_m1, cW_m2, cW_g3, cW_al,
                     cW_g4, cW_c1, cW_q, cW_k, cW_tr, cW_ao, cW_out,
                     f16s, f16s + MD, f16s + 2 * MD, f16s + 3 * MD,
                     f16s + 4 * MD, f16s + 5 * MD};
    int n4[NJOBS] = {589824, 589824, 589824, 589824, 589824, 589824, 294912, 884736,
                     147456, 147456, 147456, 147456, 147456, 147456, 147456,
                     786432, 786432, 786432, 786432, 786432, 786432};
    long total4 = 0;
    for (int i = 0; i < NJOBS; ++i) { J.src[i] = s[i]; J.dst[i] = d[i]; J.n4[i] = n4[i]; total4 += n4[i]; }
    convert_all<<<(int)((total4 + 255) / 256), 256, 0, stream>>>(J, total4);
  }
  repack_conv<<<(3 * 589824 + 255) / 256, 256, 0, stream>>>(c3_w, w3r, 3);
  repack_conv<<<(5 * 589824 + 255) / 256, 256, 0, stream>>>(c5_w, w5r, 5);

  // --- fusion weights (analytic means) ---
  for (int n = 0; n < 6; ++n)
    rowmean_kernel<<<24, 256, 0, stream>>>(f[n], rmb + (long)n * BB * DD);
  colsum_kernel<<<18, 256, 0, stream>>>(align_w, csb);
  fusion_weights<<<1, 64, 0, stream>>>(rmb, csb, align_b, att_w, att_b, wplus);

  // --- FeatureAlignment accumulated into Et with per-(b,n) row scales ---
  for (int n = 0; n < 6; ++n)
    gemm(0, 0, f16s + (long)n * MD, cW_al + (long)n * DD * DD, align_b + n * DD,
         nullptr, Et, MM, DD, DD, 0, 0, 1, 0, 0, wplus + n, 6, (n > 0) ? 1 : 0,
         1, 0, 0, 0);

  // --- GatedFusion ---
  concat_kernel<<<EW2, 256, 0, stream>>>(Et, Ea, cc);
  gemm(1, 1, cc, cW_g1, g1_b, nullptr, o1, MM, 1536, 1536, 0, 1, 1, 0, 0, nullptr, 0, 0, 1, 0, 0, 0);
  gemm(1, 1, o1, cW_g2, g2_b, nullptr, o2, MM, 1536, 1536, 0, 1, 1, 0, 0, nullptr, 0, 0, 1, 0, 0, 0);
  gemm(0, 1, o2, cW_g3, g3_b, nullptr, o3, MM, DD, 1536, 0, 1, 1, 0, 0, nullptr, 0, 0, 1, 0, 0, 0);
  gemm(0, 3, o3, cW_g4, g4_b, nullptr, gb, MM, DD, DD, 0, 1, 1, 0, 0, nullptr, 0, 0, 1, 0, 0, 0);
  ef_kernel<<<EW, 256, 0, stream>>>(gb, Ea, Et);          // Ef in place

  // --- MSFastformer front ---
  ln_kernel<<<MM, 256, 0, stream>>>(Et, 0, ln_w, ln_b, nullptr, xb16, 0);   // x
  gemm(0, 0, xb16, cW_c1, c1_b, nullptr, U1, MM, DD, DD, 0, 1, 1, 0, 0, nullptr, 0, 0, 1, 0, 0, 0);
  gemm(0, 0, xb16, w3r, c3_b, nullptr, U3, MM, DD, DD, 0, 1, 3, 1, 589824, nullptr, 0, 0, 1, 0, 0, 0);
  gemm(0, 0, xb16, w5r, c5_b, nullptr, U5, MM, DD, DD, 0, 1, 5, 2, 589824, nullptr, 0, 0, 1, 0, 0, 0);

  // --- fastformer layers (shared weights); P accumulated (bf16) ---
  auto fastformer = [&](const u16* hid, const u16* ctx, int layer) {
    gemm(0, 0, hid, cW_q, q_b, nullptr, qbuf, MM, DD, DD, 0, 1, 1, 0, 0, nullptr, 0, 0, 1, 0, 0, 0);
    gemm(0, 0, ctx, cW_k, k_b, nullptr, ctxkk, MM, DD, DD, 0, 1, 1, 0, 0, nullptr, 0, 0, 1, 0, 0, 0);
    lin_small<<<MM / 4, 256, 0, stream>>>(qbuf, qa_w, qa_b, 0.125f, qsf);
    lin_small<<<MM / 4, 256, 0, stream>>>(ctxkk, ka_w, ka_b, 0.125f, ksf);
    scores_softmax<<<MM, 256, 0, stream>>>(qsf, ksf, awb);
    transpose_kernel<<<dim3(24, 16, 8), dim3(32, 8), 0, stream>>>(ctxkk, kkTsf);
    gemm(0, 0, awb, kkTsf, nullptr, nullptr, ctxkk, TT, DD, TT, 0, 1, 1, 0, 0, nullptr, 0, 0,
         BB, (long)TT * TT, (long)DD * TT, (long)TT * DD);
    gemm(0, 0, ctxkk, cW_tr, tr_b, qbuf, kkTsf, MM, DD, DD, 1, 1, 1, 0, 0, nullptr, 0, 0, 1, 0, 0, 0);
    gemm(0, 0, kkTsf, cW_ao, ao_b, hid, attp, MM, DD, DD, 1, 1, 1, 0, 0, nullptr, 0, 0, 1, 0, 0, 0);
    ln_kernel<<<MM, 256, 0, stream>>>(attp, 1, fln_w, fln_b, nullptr, attb, 0);
    gemm(2, 2, attb, cW_fi, fi_b, nullptr, interb, MM, FFN, DD, 0, 1, 1, 0, 0, nullptr, 0, 0, 1, 0, 0, 0);
    gemm(0, 0, interb, cW_fo, fo_b, attb, outp, MM, DD, FFN, 1, 1, 1, 0, 0, nullptr, 0, 0, 1, 0, 0, 0);
    ln_kernel<<<MM, 256, 0, stream>>>(outp, 1, fln_w, fln_b, nullptr, Pacc, (layer > 0) ? 1 : 0);
  };
  fastformer(U5, U3, 0);
  fastformer(U3, U1, 1);
  fastformer(U1, U5, 2);

  // --- tail ---
  ln_kernel<<<MM, 256, 0, stream>>>(Pacc, 1, ln_w, ln_b, nullptr, Pn, 0);
  gemm(2, 2, Pn, cW_m1, m1_b, nullptr, interb, MM, FFN, DD, 0, 1, 1, 0, 0, nullptr, 0, 0, 1, 0, 0, 0);
  gemm(0, 0, interb, cW_m2, m2_b, xb16, Jb, MM, DD, FFN, 1, 0, 1, 0, 0, nullptr, 0, 0, 1, 0, 0, 0);
  ln_kernel<<<MM, 256, 0, stream>>>(Jb, 0, ln_w, ln_b, nullptr, Jn, 0);
  gemm(0, 0, Jn, cW_out, out_b, nullptr, (float*)d_out, MM, DD, DD, 0, 0, 1, 0, 0, nullptr, 0, 0, 1, 0, 0, 0);
}